// Round 1
// baseline (228.039 us; speedup 1.0000x reference)
//
#include <hip/hip_runtime.h>
#include <math.h>

// Problem: B=2048, L=64, D=512. Only out[:,0] is needed.
// Pipeline:
//   K1: q  = (x[:,0,:] + pos_e[0]) @ We_q^T + be_q            [2048,512]
//   K2: qk = q @ [We_k | Wr_k]                                [2048,1024]
//   K3: per-row scores (129) + softmax + weighted sums ce,cr  [2048,512] each
//   K4: out = ce @ We_v^T + cr @ Wr_v^T + spe*be_v + spr*br_v [2048,512]

static __device__ __forceinline__ float bf2f(unsigned short s) {
  union { unsigned u; float f; } c; c.u = ((unsigned)s) << 16; return c.f;
}
static __device__ __forceinline__ unsigned short f2bf(float f) {
  union { float f; unsigned u; } c; c.f = f;
  unsigned u = c.u;
  unsigned r = (u + 0x7fffu + ((u >> 16) & 1u)) >> 16;
  return (unsigned short)r;
}

// ---------------- K1: q = (X0 + pe0) @ We_q^T + be_q ----------------
__global__ __launch_bounds__(256) void gemm_q_kernel(
    const float* __restrict__ x, const float* __restrict__ pos_e,
    const float* __restrict__ We_q, const float* __restrict__ be_q,
    float* __restrict__ q) {
  __shared__ float As[16][64];
  __shared__ float Bs[16][64];
  const int bn = blockIdx.x * 64;   // N = 512
  const int bm = blockIdx.y * 64;   // M = 2048
  const int tid = threadIdx.x;
  const int lrow = tid >> 2;
  const int lk = (tid & 3) * 4;
  const int m0 = (tid >> 4) * 4;
  const int n0 = (tid & 15) * 4;
  float acc[4][4] = {};
  for (int k0 = 0; k0 < 512; k0 += 16) {
    float4 av = *(const float4*)(x + (size_t)(bm + lrow) * 32768 + k0 + lk);
    float4 pv = *(const float4*)(pos_e + k0 + lk);
    As[lk + 0][lrow] = av.x + pv.x;
    As[lk + 1][lrow] = av.y + pv.y;
    As[lk + 2][lrow] = av.z + pv.z;
    As[lk + 3][lrow] = av.w + pv.w;
    float4 bv = *(const float4*)(We_q + (size_t)(bn + lrow) * 512 + k0 + lk);
    Bs[lk + 0][lrow] = bv.x;
    Bs[lk + 1][lrow] = bv.y;
    Bs[lk + 2][lrow] = bv.z;
    Bs[lk + 3][lrow] = bv.w;
    __syncthreads();
#pragma unroll
    for (int k = 0; k < 16; ++k) {
      float a[4], b[4];
#pragma unroll
      for (int i = 0; i < 4; ++i) a[i] = As[k][m0 + i];
#pragma unroll
      for (int j = 0; j < 4; ++j) b[j] = Bs[k][n0 + j];
#pragma unroll
      for (int i = 0; i < 4; ++i)
#pragma unroll
        for (int j = 0; j < 4; ++j) acc[i][j] += a[i] * b[j];
    }
    __syncthreads();
  }
#pragma unroll
  for (int i = 0; i < 4; ++i) {
    float4 o;
    o.x = acc[i][0] + be_q[bn + n0 + 0];
    o.y = acc[i][1] + be_q[bn + n0 + 1];
    o.z = acc[i][2] + be_q[bn + n0 + 2];
    o.w = acc[i][3] + be_q[bn + n0 + 3];
    *(float4*)(q + (size_t)(bm + m0 + i) * 512 + bn + n0) = o;
  }
}

// ---------------- K2: qk = q @ [We_k | Wr_k]  (B not transposed) ----------------
__global__ __launch_bounds__(256) void gemm_qk_kernel(
    const float* __restrict__ q, const float* __restrict__ We_k,
    const float* __restrict__ Wr_k, float* __restrict__ qkout) {
  __shared__ float As[16][64];
  __shared__ float Bs[16][64];
  const int bn = blockIdx.x * 64;   // N = 1024
  const int bm = blockIdx.y * 64;
  const int tid = threadIdx.x;
  const int lrow = tid >> 2;
  const int lk = (tid & 3) * 4;
  const int bkrow = tid >> 4;
  const int bnc = (tid & 15) * 4;
  const int m0 = (tid >> 4) * 4;
  const int n0 = (tid & 15) * 4;
  const float* W = (bn < 512) ? We_k : Wr_k;
  const int bncol = (bn < 512) ? bn : bn - 512;
  float acc[4][4] = {};
  for (int k0 = 0; k0 < 512; k0 += 16) {
    float4 av = *(const float4*)(q + (size_t)(bm + lrow) * 512 + k0 + lk);
    As[lk + 0][lrow] = av.x;
    As[lk + 1][lrow] = av.y;
    As[lk + 2][lrow] = av.z;
    As[lk + 3][lrow] = av.w;
    float4 bv = *(const float4*)(W + (size_t)(k0 + bkrow) * 512 + bncol + bnc);
    *(float4*)&Bs[bkrow][bnc] = bv;
    __syncthreads();
#pragma unroll
    for (int k = 0; k < 16; ++k) {
      float a[4], b[4];
#pragma unroll
      for (int i = 0; i < 4; ++i) a[i] = As[k][m0 + i];
#pragma unroll
      for (int j = 0; j < 4; ++j) b[j] = Bs[k][n0 + j];
#pragma unroll
      for (int i = 0; i < 4; ++i)
#pragma unroll
        for (int j = 0; j < 4; ++j) acc[i][j] += a[i] * b[j];
    }
    __syncthreads();
  }
#pragma unroll
  for (int i = 0; i < 4; ++i) {
    float4 o;
    o.x = acc[i][0];
    o.y = acc[i][1];
    o.z = acc[i][2];
    o.w = acc[i][3];
    *(float4*)(qkout + (size_t)(bm + m0 + i) * 1024 + bn + n0) = o;
  }
}

// ---------------- K3: per-batch-row attention ----------------
__global__ __launch_bounds__(512) void attn_kernel(
    const float* __restrict__ x, const float* __restrict__ rel,
    const float* __restrict__ maskv, const float* __restrict__ pos_e,
    const float* __restrict__ pos_r, const float* __restrict__ be_k,
    const float* __restrict__ br_k, const float* __restrict__ q,
    const float* __restrict__ qk, float* __restrict__ ce,
    float* __restrict__ cr, float* __restrict__ sum_pe,
    float* __restrict__ sum_pr) {
  __shared__ unsigned short xs[64 * 512];  // bf16 bits, 64KB
  __shared__ float qke[512];
  __shared__ float qkr[512];
  __shared__ float rels[512];
  __shared__ float sc[129];
  __shared__ float pvv[129];
  __shared__ float scx[8];
  const int b = blockIdx.x;
  const int tid = threadIdx.x;
  const int wid = tid >> 6;
  const int lane = tid & 63;
  const float scale = 0.04419417382415922f;  // 1/sqrt(512)

  // stage x[b] (raw, bf16) + per-row vectors
  const float* xb = x + (size_t)b * 32768;
  for (int i = tid; i < 8192; i += 512) {
    float4 v = *(const float4*)(xb + i * 4);
    ushort4 u;
    u.x = f2bf(v.x); u.y = f2bf(v.y); u.z = f2bf(v.z); u.w = f2bf(v.w);
    *(ushort4*)&xs[i * 4] = u;
  }
  qke[tid] = qk[(size_t)b * 1024 + tid];
  qkr[tid] = qk[(size_t)b * 1024 + 512 + tid];
  rels[tid] = rel[(size_t)b * 512 + tid];
  __syncthreads();

  float qe[8], qr[8];
#pragma unroll
  for (int i = 0; i < 8; ++i) {
    qe[i] = qke[lane * 8 + i];
    qr[i] = qkr[lane * 8 + i];
  }

  // entity scores j = 0..63: dot(qk_e, x_j + pos_e_j)
  for (int j = wid; j < 64; j += 8) {
    const unsigned short* xr = &xs[j * 512 + lane * 8];
    float4 p0 = *(const float4*)(pos_e + j * 512 + lane * 8);
    float4 p1 = *(const float4*)(pos_e + j * 512 + lane * 8 + 4);
    float s = qe[0] * (bf2f(xr[0]) + p0.x) + qe[1] * (bf2f(xr[1]) + p0.y) +
              qe[2] * (bf2f(xr[2]) + p0.z) + qe[3] * (bf2f(xr[3]) + p0.w) +
              qe[4] * (bf2f(xr[4]) + p1.x) + qe[5] * (bf2f(xr[5]) + p1.y) +
              qe[6] * (bf2f(xr[6]) + p1.z) + qe[7] * (bf2f(xr[7]) + p1.w);
#pragma unroll
    for (int off = 32; off > 0; off >>= 1) s += __shfl_xor(s, off);
    if (lane == 0) sc[j] = s;
  }
  // relation positional parts: dot(qk_r, pos_r_j) -> sc[65+j]
  for (int j = wid; j < 64; j += 8) {
    float4 p0 = *(const float4*)(pos_r + j * 512 + lane * 8);
    float4 p1 = *(const float4*)(pos_r + j * 512 + lane * 8 + 4);
    float s = qr[0] * p0.x + qr[1] * p0.y + qr[2] * p0.z + qr[3] * p0.w +
              qr[4] * p1.x + qr[5] * p1.y + qr[6] * p1.z + qr[7] * p1.w;
#pragma unroll
    for (int off = 32; off > 0; off >>= 1) s += __shfl_xor(s, off);
    if (lane == 0) sc[65 + j] = s;
  }
  // extras: mask score, c_rel = dot(qk_r, rel_b), qbk = q.be_k, qbr = q.br_k
  if (wid == 0) {
    float4 m0 = *(const float4*)(maskv + lane * 8);
    float4 m1 = *(const float4*)(maskv + lane * 8 + 4);
    float4 p0 = *(const float4*)(pos_e + 64 * 512 + lane * 8);
    float4 p1 = *(const float4*)(pos_e + 64 * 512 + lane * 8 + 4);
    float s = qe[0] * (m0.x + p0.x) + qe[1] * (m0.y + p0.y) +
              qe[2] * (m0.z + p0.z) + qe[3] * (m0.w + p0.w) +
              qe[4] * (m1.x + p1.x) + qe[5] * (m1.y + p1.y) +
              qe[6] * (m1.z + p1.z) + qe[7] * (m1.w + p1.w);
#pragma unroll
    for (int off = 32; off > 0; off >>= 1) s += __shfl_xor(s, off);
    if (lane == 0) sc[64] = s;
  } else if (wid == 1) {
    float s = 0.f;
#pragma unroll
    for (int i = 0; i < 8; ++i) s += qr[i] * rels[lane * 8 + i];
#pragma unroll
    for (int off = 32; off > 0; off >>= 1) s += __shfl_xor(s, off);
    if (lane == 0) scx[0] = s;
  } else if (wid == 2) {
    float4 q0 = *(const float4*)(q + (size_t)b * 512 + lane * 8);
    float4 q1 = *(const float4*)(q + (size_t)b * 512 + lane * 8 + 4);
    float4 k0 = *(const float4*)(be_k + lane * 8);
    float4 k1 = *(const float4*)(be_k + lane * 8 + 4);
    float s = q0.x * k0.x + q0.y * k0.y + q0.z * k0.z + q0.w * k0.w +
              q1.x * k1.x + q1.y * k1.y + q1.z * k1.z + q1.w * k1.w;
#pragma unroll
    for (int off = 32; off > 0; off >>= 1) s += __shfl_xor(s, off);
    if (lane == 0) scx[1] = s;
  } else if (wid == 3) {
    float4 q0 = *(const float4*)(q + (size_t)b * 512 + lane * 8);
    float4 q1 = *(const float4*)(q + (size_t)b * 512 + lane * 8 + 4);
    float4 k0 = *(const float4*)(br_k + lane * 8);
    float4 k1 = *(const float4*)(br_k + lane * 8 + 4);
    float s = q0.x * k0.x + q0.y * k0.y + q0.z * k0.z + q0.w * k0.w +
              q1.x * k1.x + q1.y * k1.y + q1.z * k1.z + q1.w * k1.w;
#pragma unroll
    for (int off = 32; off > 0; off >>= 1) s += __shfl_xor(s, off);
    if (lane == 0) scx[2] = s;
  }
  __syncthreads();

  // softmax over 129 scores (wave 0)
  if (wid == 0) {
    const float cR = scx[0], qbk = scx[1], qbr = scx[2];
    float v1 = (sc[lane] + qbk) * scale;                 // idx lane (entity)
    float v2 = (lane == 0) ? (sc[64] + qbk) * scale      // idx 64 (entity/mask)
                           : (sc[64 + lane] + cR + qbr) * scale;  // idx 64+lane (rel)
    float v3 = (lane == 0) ? (sc[128] + cR + qbr) * scale : -1e30f;  // idx 128
    float m = fmaxf(fmaxf(v1, v2), v3);
#pragma unroll
    for (int off = 32; off > 0; off >>= 1) m = fmaxf(m, __shfl_xor(m, off));
    float e1 = __expf(v1 - m);
    float e2 = __expf(v2 - m);
    float e3 = (lane == 0) ? __expf(v3 - m) : 0.f;
    float se = e1 + ((lane == 0) ? e2 : 0.f);
    float sr = ((lane == 0) ? 0.f : e2) + e3;
#pragma unroll
    for (int off = 32; off > 0; off >>= 1) {
      se += __shfl_xor(se, off);
      sr += __shfl_xor(sr, off);
    }
    float inv = 1.f / (se + sr);
    pvv[lane] = e1 * inv;
    pvv[64 + lane] = e2 * inv;
    if (lane == 0) {
      pvv[128] = e3 * inv;
      scx[3] = se * inv;
      scx[4] = sr * inv;
      sum_pe[b] = se * inv;
      sum_pr[b] = sr * inv;
    }
  }
  __syncthreads();

  // weighted sums: ce = sum_j<64 p_j (x_j+pos_e_j) + p64*(mask+pos_e_64)
  //                cr = (sum pr)*rel_b + sum_j pr_j pos_r_j
  {
    const int t = tid;
    float a1 = 0.f;
    for (int j = 0; j < 64; ++j) a1 += pvv[j] * bf2f(xs[j * 512 + t]);
    for (int j = 0; j < 65; ++j) a1 += pvv[j] * pos_e[j * 512 + t];
    a1 += pvv[64] * maskv[t];
    ce[(size_t)b * 512 + t] = a1;
    float a2 = scx[4] * rels[t];
    for (int j = 0; j < 64; ++j) a2 += pvv[65 + j] * pos_r[j * 512 + t];
    cr[(size_t)b * 512 + t] = a2;
  }
}

// ---------------- K4: out = ce@We_v^T + cr@Wr_v^T + spe*be_v + spr*br_v ----------------
__global__ __launch_bounds__(256) void gemm_out_kernel(
    const float* __restrict__ ce, const float* __restrict__ cr,
    const float* __restrict__ We_v, const float* __restrict__ Wr_v,
    const float* __restrict__ be_v, const float* __restrict__ br_v,
    const float* __restrict__ sum_pe, const float* __restrict__ sum_pr,
    float* __restrict__ outp) {
  __shared__ float As[16][64];
  __shared__ float Bs[16][64];
  const int bn = blockIdx.x * 64;   // N = 512
  const int bm = blockIdx.y * 64;   // M = 2048
  const int tid = threadIdx.x;
  const int lrow = tid >> 2;
  const int lk = (tid & 3) * 4;
  const int m0 = (tid >> 4) * 4;
  const int n0 = (tid & 15) * 4;
  float acc[4][4] = {};
  for (int k0 = 0; k0 < 1024; k0 += 16) {
    const float* Ap = (k0 < 512) ? ce : cr;
    const float* Bp = (k0 < 512) ? We_v : Wr_v;
    const int kk = (k0 < 512) ? k0 : k0 - 512;
    float4 av = *(const float4*)(Ap + (size_t)(bm + lrow) * 512 + kk + lk);
    As[lk + 0][lrow] = av.x;
    As[lk + 1][lrow] = av.y;
    As[lk + 2][lrow] = av.z;
    As[lk + 3][lrow] = av.w;
    float4 bv = *(const float4*)(Bp + (size_t)(bn + lrow) * 512 + kk + lk);
    Bs[lk + 0][lrow] = bv.x;
    Bs[lk + 1][lrow] = bv.y;
    Bs[lk + 2][lrow] = bv.z;
    Bs[lk + 3][lrow] = bv.w;
    __syncthreads();
#pragma unroll
    for (int k = 0; k < 16; ++k) {
      float a[4], b[4];
#pragma unroll
      for (int i = 0; i < 4; ++i) a[i] = As[k][m0 + i];
#pragma unroll
      for (int j = 0; j < 4; ++j) b[j] = Bs[k][n0 + j];
#pragma unroll
      for (int i = 0; i < 4; ++i)
#pragma unroll
        for (int j = 0; j < 4; ++j) acc[i][j] += a[i] * b[j];
    }
    __syncthreads();
  }
#pragma unroll
  for (int i = 0; i < 4; ++i) {
    const int m = bm + m0 + i;
    const float spe = sum_pe[m];
    const float spr = sum_pr[m];
    float4 o;
    o.x = acc[i][0] + spe * be_v[bn + n0 + 0] + spr * br_v[bn + n0 + 0];
    o.y = acc[i][1] + spe * be_v[bn + n0 + 1] + spr * br_v[bn + n0 + 1];
    o.z = acc[i][2] + spe * be_v[bn + n0 + 2] + spr * br_v[bn + n0 + 2];
    o.w = acc[i][3] + spe * be_v[bn + n0 + 3] + spr * br_v[bn + n0 + 3];
    *(float4*)(outp + (size_t)m * 512 + bn + n0) = o;
  }
}

extern "C" void kernel_launch(void* const* d_in, const int* in_sizes, int n_in,
                              void* d_out, int out_size, void* d_ws, size_t ws_size,
                              hipStream_t stream) {
  const float* x     = (const float*)d_in[0];   // [2048,64,512]
  const float* rel   = (const float*)d_in[1];   // [2048,512]
  const float* maskv = (const float*)d_in[2];   // [1,512]
  const float* pos_e = (const float*)d_in[3];   // [100,512]
  const float* pos_r = (const float*)d_in[4];   // [100,512]
  const float* We_q  = (const float*)d_in[5];
  const float* be_q  = (const float*)d_in[6];
  const float* We_k  = (const float*)d_in[7];
  const float* be_k  = (const float*)d_in[8];
  const float* We_v  = (const float*)d_in[9];
  const float* be_v  = (const float*)d_in[10];
  // d_in[11], d_in[12] (Wr_q, br_q) do not affect out[:,0]
  const float* Wr_k  = (const float*)d_in[13];
  const float* br_k  = (const float*)d_in[14];
  const float* Wr_v  = (const float*)d_in[15];
  const float* br_v  = (const float*)d_in[16];

  float* ws = (float*)d_ws;
  float* q    = ws;                       // 2048*512
  float* qk   = q + 1048576;              // 2048*1024
  float* ce   = qk + 2097152;             // 2048*512
  float* cr   = ce + 1048576;             // 2048*512
  float* spe  = cr + 1048576;             // 2048
  float* spr  = spe + 2048;               // 2048
  float* outp = (float*)d_out;

  gemm_q_kernel<<<dim3(8, 32), 256, 0, stream>>>(x, pos_e, We_q, be_q, q);
  gemm_qk_kernel<<<dim3(16, 32), 256, 0, stream>>>(q, We_k, Wr_k, qk);
  attn_kernel<<<dim3(2048), 512, 0, stream>>>(x, rel, maskv, pos_e, pos_r,
                                              be_k, br_k, q, qk, ce, cr, spe, spr);
  gemm_out_kernel<<<dim3(8, 32), 256, 0, stream>>>(ce, cr, We_v, Wr_v, be_v,
                                                   br_v, spe, spr, outp);
}

// Round 2
// 193.282 us; speedup vs baseline: 1.1798x; 1.1798x over previous
//
#include <hip/hip_runtime.h>
#include <math.h>

// B=2048, L=64, D=512. Only out[:,0] needed.
// Fold: q = (x0+pe0)@We_q^T + be_q appears only via qk = q@[We_k|Wr_k] and
// scalars q.be_k, q.br_k. Precompute M = We_q^T@[We_k|Wr_k] (512x1024),
// bias_e[n] = be_q@Wk[:,n], u_bk = We_q^T be_k, u_br = We_q^T br_k,
// c_bk = be_q.be_k, c_br = be_q.br_k. Then:
//   qk[m] = Xp[m] @ M + bias_e,  Xp = x[:,0,:]+pe0 (bf16)
// attn: scores/softmax/weighted sums -> ce|cr (bf16), spe, spr
// out = [ce|cr] @ [We_v|Wr_v]^T + spe*be_v + spr*br_v  (MFMA bf16)

using s16x8 = __attribute__((ext_vector_type(8))) short;
using f32x4 = __attribute__((ext_vector_type(4))) float;

static __device__ __forceinline__ float bf2f(unsigned short s) {
  union { unsigned u; float f; } c; c.u = ((unsigned)s) << 16; return c.f;
}
static __device__ __forceinline__ unsigned short f2bf(float f) {
  union { float f; unsigned u; } c; c.f = f;
  unsigned u = c.u;
  unsigned r = (u + 0x7fffu + ((u >> 16) & 1u)) >> 16;
  return (unsigned short)r;
}

// ---------------- prep: Xp (bf16), Wvb (bf16), aux vectors ----------------
__global__ __launch_bounds__(256) void prep_kernel(
    const float* __restrict__ x, const float* __restrict__ pos_e,
    const float* __restrict__ We_v, const float* __restrict__ Wr_v,
    const float* __restrict__ be_q, const float* __restrict__ We_k,
    const float* __restrict__ Wr_k, const float* __restrict__ We_q,
    const float* __restrict__ be_k, const float* __restrict__ br_k,
    unsigned short* __restrict__ Xp, unsigned short* __restrict__ Wvb,
    float* __restrict__ bias_e, float* __restrict__ u_bk,
    float* __restrict__ u_br, float* __restrict__ consts) {
  const int blk = blockIdx.x, tid = threadIdx.x;
  if (blk < 2048) {
    // Xp[m] = bf16(x[m,0,:] + pe0)
    float2 v = *(const float2*)(x + (size_t)blk * 32768 + tid * 2);
    float2 p = *(const float2*)(pos_e + tid * 2);
    ushort2 o;
    o.x = f2bf(v.x + p.x);
    o.y = f2bf(v.y + p.y);
    *(ushort2*)(Xp + (size_t)blk * 512 + tid * 2) = o;
  } else if (blk < 2560) {
    // Wvb[n][k] = bf16( k<512 ? We_v[n][k] : Wr_v[n][k-512] ),  n<512, k<1024
    const int base = ((blk - 2048) * 256 + tid) * 4;  // < 524288
    const int n = base >> 10, k = base & 1023;
    const float* src = (k < 512) ? (We_v + (size_t)n * 512 + k)
                                 : (Wr_v + (size_t)n * 512 + k - 512);
    float4 v = *(const float4*)src;
    ushort4 o;
    o.x = f2bf(v.x); o.y = f2bf(v.y); o.z = f2bf(v.z); o.w = f2bf(v.w);
    *(ushort4*)(Wvb + base) = o;
  } else {
    const int id = (blk - 2560) * 256 + tid;  // 0..2047
    if (id < 1024) {
      const float* W = (id < 512) ? We_k : Wr_k;
      const int n = (id < 512) ? id : id - 512;
      float s = 0.f;
      for (int f = 0; f < 512; ++f) s += be_q[f] * W[(size_t)f * 512 + n];
      bias_e[id] = s;
    } else if (id < 1536) {
      const int d = id - 1024;
      float s = 0.f;
      for (int f = 0; f < 512; ++f) s += We_q[(size_t)f * 512 + d] * be_k[f];
      u_bk[d] = s;
    } else {
      const int d = id - 1536;
      float s = 0.f;
      for (int f = 0; f < 512; ++f) s += We_q[(size_t)f * 512 + d] * br_k[f];
      u_br[d] = s;
    }
    if (blk == 2560 && tid == 0) {
      float s1 = 0.f, s2 = 0.f;
      for (int f = 0; f < 512; ++f) {
        s1 += be_q[f] * be_k[f];
        s2 += be_q[f] * br_k[f];
      }
      consts[0] = s1;
      consts[1] = s2;
    }
  }
}

// ------------- Wt[n][d] = sum_f We_q[f][d] * Wkc[f][n]  (bf16 out) -------------
__global__ __launch_bounds__(256) void wt_gemm_kernel(
    const float* __restrict__ We_q, const float* __restrict__ We_k,
    const float* __restrict__ Wr_k, unsigned short* __restrict__ Wt) {
  __shared__ float As[16][64];  // [f][d]
  __shared__ float Bs[16][64];  // [f][n]
  const int bn = blockIdx.x * 64;  // n over 1024
  const int bd = blockIdx.y * 64;  // d over 512
  const int tid = threadIdx.x;
  const int fr = tid >> 4;
  const int c4 = (tid & 15) * 4;
  const int dt = (tid >> 4) * 4;
  const int nt = (tid & 15) * 4;
  const float* Wkc = (bn < 512) ? We_k : Wr_k;
  const int bnc = (bn < 512) ? bn : bn - 512;
  float acc[4][4] = {};
  for (int f0 = 0; f0 < 512; f0 += 16) {
    *(float4*)&As[fr][c4] = *(const float4*)(We_q + (size_t)(f0 + fr) * 512 + bd + c4);
    *(float4*)&Bs[fr][c4] = *(const float4*)(Wkc + (size_t)(f0 + fr) * 512 + bnc + c4);
    __syncthreads();
#pragma unroll
    for (int k = 0; k < 16; ++k) {
      float a[4], b[4];
#pragma unroll
      for (int i = 0; i < 4; ++i) a[i] = As[k][dt + i];
#pragma unroll
      for (int j = 0; j < 4; ++j) b[j] = Bs[k][nt + j];
#pragma unroll
      for (int i = 0; i < 4; ++i)
#pragma unroll
        for (int j = 0; j < 4; ++j) acc[i][j] += a[i] * b[j];
    }
    __syncthreads();
  }
#pragma unroll
  for (int j = 0; j < 4; ++j)
#pragma unroll
    for (int i = 0; i < 4; ++i)
      Wt[(size_t)(bn + nt + j) * 512 + bd + dt + i] = f2bf(acc[i][j]);
}

// ---------------- qk = Xp @ Wt^T + bias_e   (MFMA bf16) ----------------
// qk[m][n] = sum_d Xp[m][d] * Wt[n][d];  A,B both contiguous in k(=d).
__global__ __launch_bounds__(256) void qk_mfma_kernel(
    const unsigned short* __restrict__ Xp, const unsigned short* __restrict__ Wt,
    const float* __restrict__ bias_e, float* __restrict__ qk) {
  const int bn = blockIdx.x * 64;  // N=1024
  const int bm = blockIdx.y * 64;  // M=2048
  const int tid = threadIdx.x;
  const int wid = tid >> 6, lane = tid & 63;
  const int wm = (wid >> 1) * 32, wn = (wid & 1) * 32;
  const int lr = lane & 15, koff = (lane >> 4) * 8;
  f32x4 acc[2][2] = {};
  for (int k0 = 0; k0 < 512; k0 += 32) {
    s16x8 a[2], b[2];
#pragma unroll
    for (int im = 0; im < 2; ++im)
      a[im] = *(const s16x8*)(Xp + (size_t)(bm + wm + im * 16 + lr) * 512 + k0 + koff);
#pragma unroll
    for (int in = 0; in < 2; ++in)
      b[in] = *(const s16x8*)(Wt + (size_t)(bn + wn + in * 16 + lr) * 512 + k0 + koff);
#pragma unroll
    for (int im = 0; im < 2; ++im)
#pragma unroll
      for (int in = 0; in < 2; ++in)
        acc[im][in] = __builtin_amdgcn_mfma_f32_16x16x32_bf16(a[im], b[in], acc[im][in], 0, 0, 0);
  }
  const int r0 = (lane >> 4) * 4;
#pragma unroll
  for (int im = 0; im < 2; ++im)
#pragma unroll
    for (int in = 0; in < 2; ++in)
#pragma unroll
      for (int i = 0; i < 4; ++i) {
        const int row = bm + wm + im * 16 + r0 + i;
        const int col = bn + wn + in * 16 + lr;
        qk[(size_t)row * 1024 + col] = acc[im][in][i] + bias_e[col];
      }
}

// ---------------- attn: scores + softmax + weighted sums ----------------
__global__ __launch_bounds__(512) void attn_kernel(
    const float* __restrict__ x, const float* __restrict__ rel,
    const float* __restrict__ maskv, const float* __restrict__ pos_e,
    const float* __restrict__ pos_r, const unsigned short* __restrict__ Xp,
    const float* __restrict__ u_bk, const float* __restrict__ u_br,
    const float* __restrict__ consts, const float* __restrict__ qk,
    unsigned short* __restrict__ cecr, float* __restrict__ sum_pe,
    float* __restrict__ sum_pr) {
  __shared__ unsigned short xs[64 * 512];   // 64 KB: x[b] rows in bf16
  __shared__ unsigned short part[8 * 512];  // 8 KB: per-wave partials (bf16)
  __shared__ float sc[129];
  __shared__ float pvv[129];
  __shared__ float scx[8];
  const int b = blockIdx.x;
  const int tid = threadIdx.x;
  const int wid = tid >> 6, lane = tid & 63;
  const float scale = 0.04419417382415922f;  // 1/sqrt(512)

  // stage x[b] as bf16
  const float* xb = x + (size_t)b * 32768;
  for (int i = tid; i < 8192; i += 512) {
    float4 v = *(const float4*)(xb + i * 4);
    ushort4 u;
    u.x = f2bf(v.x); u.y = f2bf(v.y); u.z = f2bf(v.z); u.w = f2bf(v.w);
    *(ushort4*)(xs + i * 4) = u;
  }
  // per-lane qk vectors from global (all waves read same 4 KB -> L1)
  float qe[8], qr[8];
  {
    float4 a0 = *(const float4*)(qk + (size_t)b * 1024 + lane * 8);
    float4 a1 = *(const float4*)(qk + (size_t)b * 1024 + lane * 8 + 4);
    float4 r0 = *(const float4*)(qk + (size_t)b * 1024 + 512 + lane * 8);
    float4 r1 = *(const float4*)(qk + (size_t)b * 1024 + 512 + lane * 8 + 4);
    qe[0] = a0.x; qe[1] = a0.y; qe[2] = a0.z; qe[3] = a0.w;
    qe[4] = a1.x; qe[5] = a1.y; qe[6] = a1.z; qe[7] = a1.w;
    qr[0] = r0.x; qr[1] = r0.y; qr[2] = r0.z; qr[3] = r0.w;
    qr[4] = r1.x; qr[5] = r1.y; qr[6] = r1.z; qr[7] = r1.w;
  }
  __syncthreads();

  // entity scores j=0..63: dot(qk_e, x_j + pos_e_j)
  for (int j = wid; j < 64; j += 8) {
    const unsigned short* xr = xs + j * 512 + lane * 8;
    float4 p0 = *(const float4*)(pos_e + (size_t)j * 512 + lane * 8);
    float4 p1 = *(const float4*)(pos_e + (size_t)j * 512 + lane * 8 + 4);
    float s = qe[0] * (bf2f(xr[0]) + p0.x) + qe[1] * (bf2f(xr[1]) + p0.y) +
              qe[2] * (bf2f(xr[2]) + p0.z) + qe[3] * (bf2f(xr[3]) + p0.w) +
              qe[4] * (bf2f(xr[4]) + p1.x) + qe[5] * (bf2f(xr[5]) + p1.y) +
              qe[6] * (bf2f(xr[6]) + p1.z) + qe[7] * (bf2f(xr[7]) + p1.w);
#pragma unroll
    for (int off = 32; off > 0; off >>= 1) s += __shfl_xor(s, off);
    if (lane == 0) sc[j] = s;
  }
  // relation positional parts: dot(qk_r, pos_r_j)
  for (int j = wid; j < 64; j += 8) {
    float4 p0 = *(const float4*)(pos_r + (size_t)j * 512 + lane * 8);
    float4 p1 = *(const float4*)(pos_r + (size_t)j * 512 + lane * 8 + 4);
    float s = qr[0] * p0.x + qr[1] * p0.y + qr[2] * p0.z + qr[3] * p0.w +
              qr[4] * p1.x + qr[5] * p1.y + qr[6] * p1.z + qr[7] * p1.w;
#pragma unroll
    for (int off = 32; off > 0; off >>= 1) s += __shfl_xor(s, off);
    if (lane == 0) sc[65 + j] = s;
  }
  // extras
  if (wid == 0) {  // mask-token score (index 64)
    float4 m0 = *(const float4*)(maskv + lane * 8);
    float4 m1 = *(const float4*)(maskv + lane * 8 + 4);
    float4 p0 = *(const float4*)(pos_e + 64 * 512 + lane * 8);
    float4 p1 = *(const float4*)(pos_e + 64 * 512 + lane * 8 + 4);
    float s = qe[0] * (m0.x + p0.x) + qe[1] * (m0.y + p0.y) +
              qe[2] * (m0.z + p0.z) + qe[3] * (m0.w + p0.w) +
              qe[4] * (m1.x + p1.x) + qe[5] * (m1.y + p1.y) +
              qe[6] * (m1.z + p1.z) + qe[7] * (m1.w + p1.w);
#pragma unroll
    for (int off = 32; off > 0; off >>= 1) s += __shfl_xor(s, off);
    if (lane == 0) sc[64] = s;
  } else if (wid == 1) {  // c_rel = dot(qk_r, rel_b)
    float4 r0 = *(const float4*)(rel + (size_t)b * 512 + lane * 8);
    float4 r1 = *(const float4*)(rel + (size_t)b * 512 + lane * 8 + 4);
    float s = qr[0] * r0.x + qr[1] * r0.y + qr[2] * r0.z + qr[3] * r0.w +
              qr[4] * r1.x + qr[5] * r1.y + qr[6] * r1.z + qr[7] * r1.w;
#pragma unroll
    for (int off = 32; off > 0; off >>= 1) s += __shfl_xor(s, off);
    if (lane == 0) scx[0] = s;
  } else if (wid == 2) {  // qbk = Xp[b].u_bk + c_bk
    const unsigned short* xp = Xp + (size_t)b * 512 + lane * 8;
    float4 u0 = *(const float4*)(u_bk + lane * 8);
    float4 u1 = *(const float4*)(u_bk + lane * 8 + 4);
    float s = bf2f(xp[0]) * u0.x + bf2f(xp[1]) * u0.y + bf2f(xp[2]) * u0.z +
              bf2f(xp[3]) * u0.w + bf2f(xp[4]) * u1.x + bf2f(xp[5]) * u1.y +
              bf2f(xp[6]) * u1.z + bf2f(xp[7]) * u1.w;
#pragma unroll
    for (int off = 32; off > 0; off >>= 1) s += __shfl_xor(s, off);
    if (lane == 0) scx[1] = s + consts[0];
  } else if (wid == 3) {  // qbr = Xp[b].u_br + c_br
    const unsigned short* xp = Xp + (size_t)b * 512 + lane * 8;
    float4 u0 = *(const float4*)(u_br + lane * 8);
    float4 u1 = *(const float4*)(u_br + lane * 8 + 4);
    float s = bf2f(xp[0]) * u0.x + bf2f(xp[1]) * u0.y + bf2f(xp[2]) * u0.z +
              bf2f(xp[3]) * u0.w + bf2f(xp[4]) * u1.x + bf2f(xp[5]) * u1.y +
              bf2f(xp[6]) * u1.z + bf2f(xp[7]) * u1.w;
#pragma unroll
    for (int off = 32; off > 0; off >>= 1) s += __shfl_xor(s, off);
    if (lane == 0) scx[2] = s + consts[1];
  }
  __syncthreads();

  // softmax over 129 scores (wave 0)
  if (wid == 0) {
    const float cR = scx[0], qbk = scx[1], qbr = scx[2];
    float v1 = (sc[lane] + qbk) * scale;
    float v2 = (lane == 0) ? (sc[64] + qbk) * scale
                           : (sc[64 + lane] + cR + qbr) * scale;
    float v3 = (lane == 0) ? (sc[128] + cR + qbr) * scale : -1e30f;
    float m = fmaxf(fmaxf(v1, v2), v3);
#pragma unroll
    for (int off = 32; off > 0; off >>= 1) m = fmaxf(m, __shfl_xor(m, off));
    float e1 = __expf(v1 - m);
    float e2 = __expf(v2 - m);
    float e3 = (lane == 0) ? __expf(v3 - m) : 0.f;
    float se = e1 + ((lane == 0) ? e2 : 0.f);
    float sr = ((lane == 0) ? 0.f : e2) + e3;
#pragma unroll
    for (int off = 32; off > 0; off >>= 1) {
      se += __shfl_xor(se, off);
      sr += __shfl_xor(sr, off);
    }
    float inv = 1.f / (se + sr);
    pvv[lane] = e1 * inv;
    pvv[64 + lane] = e2 * inv;
    if (lane == 0) {
      pvv[128] = e3 * inv;
      scx[3] = se * inv;
      scx[4] = sr * inv;
      sum_pe[b] = se * inv;
      sum_pr[b] = sr * inv;
    }
  }
  __syncthreads();

  // entity weighted sums: wave w owns rows j = 8w..8w+7, lane owns 8 d-cols
  {
    float a[8] = {};
    const int j0 = wid * 8;
#pragma unroll
    for (int jj = 0; jj < 8; ++jj) {
      const int j = j0 + jj;
      const float p = pvv[j];
      const unsigned short* xr = xs + j * 512 + lane * 8;
      float4 p0 = *(const float4*)(pos_e + (size_t)j * 512 + lane * 8);
      float4 p1 = *(const float4*)(pos_e + (size_t)j * 512 + lane * 8 + 4);
      a[0] += p * (bf2f(xr[0]) + p0.x);
      a[1] += p * (bf2f(xr[1]) + p0.y);
      a[2] += p * (bf2f(xr[2]) + p0.z);
      a[3] += p * (bf2f(xr[3]) + p0.w);
      a[4] += p * (bf2f(xr[4]) + p1.x);
      a[5] += p * (bf2f(xr[5]) + p1.y);
      a[6] += p * (bf2f(xr[6]) + p1.z);
      a[7] += p * (bf2f(xr[7]) + p1.w);
    }
    ushort4 o0, o1;
    o0.x = f2bf(a[0]); o0.y = f2bf(a[1]); o0.z = f2bf(a[2]); o0.w = f2bf(a[3]);
    o1.x = f2bf(a[4]); o1.y = f2bf(a[5]); o1.z = f2bf(a[6]); o1.w = f2bf(a[7]);
    *(ushort4*)(part + wid * 512 + lane * 8) = o0;
    *(ushort4*)(part + wid * 512 + lane * 8 + 4) = o1;
  }
  __syncthreads();
  {
    const int t = tid;
    float s = 0.f;
#pragma unroll
    for (int w = 0; w < 8; ++w) s += bf2f(part[w * 512 + t]);
    s += pvv[64] * (maskv[t] + pos_e[64 * 512 + t]);
    cecr[(size_t)b * 1024 + t] = f2bf(s);
  }
  __syncthreads();

  // relation weighted sums
  {
    float a[8] = {};
    const int j0 = wid * 8;
#pragma unroll
    for (int jj = 0; jj < 8; ++jj) {
      const int j = j0 + jj;
      const float p = pvv[65 + j];
      float4 p0 = *(const float4*)(pos_r + (size_t)j * 512 + lane * 8);
      float4 p1 = *(const float4*)(pos_r + (size_t)j * 512 + lane * 8 + 4);
      a[0] += p * p0.x; a[1] += p * p0.y; a[2] += p * p0.z; a[3] += p * p0.w;
      a[4] += p * p1.x; a[5] += p * p1.y; a[6] += p * p1.z; a[7] += p * p1.w;
    }
    ushort4 o0, o1;
    o0.x = f2bf(a[0]); o0.y = f2bf(a[1]); o0.z = f2bf(a[2]); o0.w = f2bf(a[3]);
    o1.x = f2bf(a[4]); o1.y = f2bf(a[5]); o1.z = f2bf(a[6]); o1.w = f2bf(a[7]);
    *(ushort4*)(part + wid * 512 + lane * 8) = o0;
    *(ushort4*)(part + wid * 512 + lane * 8 + 4) = o1;
  }
  __syncthreads();
  {
    const int t = tid;
    float s = 0.f;
#pragma unroll
    for (int w = 0; w < 8; ++w) s += bf2f(part[w * 512 + t]);
    s += scx[4] * rel[(size_t)b * 512 + t];
    cecr[(size_t)b * 1024 + 512 + t] = f2bf(s);
  }
}

// --------- out = [ce|cr] @ Wvb^T + spe*be_v + spr*br_v  (MFMA bf16) ---------
__global__ __launch_bounds__(256) void out_mfma_kernel(
    const unsigned short* __restrict__ cecr, const unsigned short* __restrict__ Wvb,
    const float* __restrict__ be_v, const float* __restrict__ br_v,
    const float* __restrict__ spe, const float* __restrict__ spr,
    float* __restrict__ outp) {
  const int bn = blockIdx.x * 64;  // N=512
  const int bm = blockIdx.y * 64;  // M=2048
  const int tid = threadIdx.x;
  const int wid = tid >> 6, lane = tid & 63;
  const int wm = (wid >> 1) * 32, wn = (wid & 1) * 32;
  const int lr = lane & 15, koff = (lane >> 4) * 8;
  f32x4 acc[2][2] = {};
  for (int k0 = 0; k0 < 1024; k0 += 32) {
    s16x8 a[2], b[2];
#pragma unroll
    for (int im = 0; im < 2; ++im)
      a[im] = *(const s16x8*)(cecr + (size_t)(bm + wm + im * 16 + lr) * 1024 + k0 + koff);
#pragma unroll
    for (int in = 0; in < 2; ++in)
      b[in] = *(const s16x8*)(Wvb + (size_t)(bn + wn + in * 16 + lr) * 1024 + k0 + koff);
#pragma unroll
    for (int im = 0; im < 2; ++im)
#pragma unroll
      for (int in = 0; in < 2; ++in)
        acc[im][in] = __builtin_amdgcn_mfma_f32_16x16x32_bf16(a[im], b[in], acc[im][in], 0, 0, 0);
  }
  const int r0 = (lane >> 4) * 4;
#pragma unroll
  for (int im = 0; im < 2; ++im)
#pragma unroll
    for (int i = 0; i < 4; ++i) {
      const int row = bm + wm + im * 16 + r0 + i;
      const float se = spe[row], sr = spr[row];
#pragma unroll
      for (int in = 0; in < 2; ++in) {
        const int col = bn + wn + in * 16 + lr;
        outp[(size_t)row * 512 + col] = acc[im][in][i] + se * be_v[col] + sr * br_v[col];
      }
    }
}

extern "C" void kernel_launch(void* const* d_in, const int* in_sizes, int n_in,
                              void* d_out, int out_size, void* d_ws, size_t ws_size,
                              hipStream_t stream) {
  const float* x     = (const float*)d_in[0];   // [2048,64,512]
  const float* rel   = (const float*)d_in[1];   // [2048,512]
  const float* maskv = (const float*)d_in[2];   // [1,512]
  const float* pos_e = (const float*)d_in[3];   // [100,512]
  const float* pos_r = (const float*)d_in[4];   // [100,512]
  const float* We_q  = (const float*)d_in[5];
  const float* be_q  = (const float*)d_in[6];
  const float* We_k  = (const float*)d_in[7];
  const float* be_k  = (const float*)d_in[8];
  const float* We_v  = (const float*)d_in[9];
  const float* be_v  = (const float*)d_in[10];
  // d_in[11], d_in[12] (Wr_q, br_q) do not affect out[:,0]
  const float* Wr_k  = (const float*)d_in[13];
  const float* br_k  = (const float*)d_in[14];
  const float* Wr_v  = (const float*)d_in[15];
  const float* br_v  = (const float*)d_in[16];

  float* fws = (float*)d_ws;
  float* qk     = fws;                 // 2048*1024
  float* spe    = qk + 2097152;        // 2048
  float* spr    = spe + 2048;          // 2048
  float* bias_e = spr + 2048;          // 1024
  float* u_bk   = bias_e + 1024;       // 512
  float* u_br   = u_bk + 512;          // 512
  float* consts = u_br + 512;          // 4
  unsigned short* Wt   = (unsigned short*)(consts + 4);  // [1024][512]
  unsigned short* Wvb  = Wt + 524288;                    // [512][1024]
  unsigned short* Xp   = Wvb + 524288;                   // [2048][512]
  unsigned short* cecr = Xp + 1048576;                   // [2048][1024]
  float* outp = (float*)d_out;

  prep_kernel<<<2568, 256, 0, stream>>>(x, pos_e, We_v, Wr_v, be_q, We_k, Wr_k,
                                        We_q, be_k, br_k, Xp, Wvb, bias_e,
                                        u_bk, u_br, consts);
  wt_gemm_kernel<<<dim3(16, 8), 256, 0, stream>>>(We_q, We_k, Wr_k, Wt);
  qk_mfma_kernel<<<dim3(16, 32), 256, 0, stream>>>(Xp, Wt, bias_e, qk);
  attn_kernel<<<dim3(2048), 512, 0, stream>>>(x, rel, maskv, pos_e, pos_r, Xp,
                                              u_bk, u_br, consts, qk, cecr,
                                              spe, spr);
  out_mfma_kernel<<<dim3(8, 32), 256, 0, stream>>>(cecr, Wvb, be_v, br_v, spe,
                                                   spr, outp);
}